// Round 1
// baseline (838.417 us; speedup 1.0000x reference)
//
#include <hip/hip_runtime.h>

// VDPDropout: B=32, H=2048, DROP_PROP=0.2
//   mu_out[b,h]      = keep[b,h] ? mu_in[b,h] * 1.25f : 0
//   nz[b,h]          = keep[b,h] && (mu_in[b,h] != 0)
//   Sigma_out[b,i,j] = (nz[b,i] && nz[b,j]) ? 1.5625f * Sigma_in[b,i,j] : 0
//
// float32(1.0/0.8)   == 1.25f   exactly (double 1.2499999999999999 rounds to 1.25f)
// float32((1/0.8)^2) == 1.5625f exactly
// so fp32 constants reproduce the reference bit-for-bit on normal inputs.

#define SCALE  1.25f
#define SCALE2 1.5625f

#define B_DIM 32
#define H_DIM 2048

__global__ void mu_kernel(const float* __restrict__ mu_in,
                          const int* __restrict__ keep,
                          float* __restrict__ mu_out, int n) {
    int i = blockIdx.x * blockDim.x + threadIdx.x;
    if (i < n) {
        float m = mu_in[i];
        mu_out[i] = keep[i] ? m * SCALE : 0.0f;
    }
}

// One float4 of Sigma per thread. gid indexes float4s of the flat [B*H*H] array.
// Row r = gid / (H/4) in [0, B*H); batch b = r / H; column-float4 c4 = gid % (H/4).
__global__ void sigma_kernel(const float* __restrict__ mu_in,
                             const int* __restrict__ keep,
                             const float* __restrict__ Sigma_in,
                             float* __restrict__ Sigma_out) {
    const int H4 = H_DIM / 4;  // 512 float4s per row
    long long gid = (long long)blockIdx.x * blockDim.x + threadIdx.x;
    const long long total = (long long)B_DIM * H_DIM * H4;  // 33,554,432
    if (gid >= total) return;

    int r  = (int)(gid >> 9);        // gid / 512  -> flat row index in [0, B*H)
    int c4 = (int)(gid & (H4 - 1));  // column float4 index
    int b  = r >> 11;                // r / 2048

    // row factor: nz[b,i]
    bool nzi = (keep[r] != 0) && (mu_in[r] != 0.0f);

    // column factors: nz[b, 4*c4 .. 4*c4+3] (cached loads, keep+mu fit in L2)
    int col_base4 = b * 512 + c4;  // float4/int4 index into [B*H] arrays
    const int4*   keep4 = (const int4*)keep;
    const float4* mu4   = (const float4*)mu_in;
    int4   kj = keep4[col_base4];
    float4 mj = mu4[col_base4];

    const float4* Sin4  = (const float4*)Sigma_in;
    float4*       Sout4 = (float4*)Sigma_out;
    float4 s = Sin4[gid];

    float4 o;
    o.x = (nzi && kj.x != 0 && mj.x != 0.0f) ? SCALE2 * s.x : 0.0f;
    o.y = (nzi && kj.y != 0 && mj.y != 0.0f) ? SCALE2 * s.y : 0.0f;
    o.z = (nzi && kj.z != 0 && mj.z != 0.0f) ? SCALE2 * s.z : 0.0f;
    o.w = (nzi && kj.w != 0 && mj.w != 0.0f) ? SCALE2 * s.w : 0.0f;
    Sout4[gid] = o;
}

extern "C" void kernel_launch(void* const* d_in, const int* in_sizes, int n_in,
                              void* d_out, int out_size, void* d_ws, size_t ws_size,
                              hipStream_t stream) {
    const float* mu_in    = (const float*)d_in[0];
    const float* Sigma_in = (const float*)d_in[1];
    const int*   keep     = (const int*)d_in[2];

    float* mu_out    = (float*)d_out;
    float* Sigma_out = (float*)d_out + (B_DIM * H_DIM);  // 65536-float offset, 16B-aligned

    // mu_out: 65536 elements
    {
        int n = B_DIM * H_DIM;
        int threads = 256;
        int blocks = (n + threads - 1) / threads;
        mu_kernel<<<blocks, threads, 0, stream>>>(mu_in, keep, mu_out, n);
    }

    // Sigma_out: 134,217,728 elements = 33,554,432 float4s
    {
        long long total4 = (long long)B_DIM * H_DIM * (H_DIM / 4);
        int threads = 256;
        long long blocks = (total4 + threads - 1) / threads;  // 131072
        sigma_kernel<<<(int)blocks, threads, 0, stream>>>(mu_in, keep, Sigma_in, Sigma_out);
    }
}